// Round 7
// baseline (294.672 us; speedup 1.0000x reference)
//
#include <hip/hip_runtime.h>
#include <cstdint>

#define R_TOT 16384
#define T_NT  2048
#define DD    128
#define HH    512
#define MC_   20
#define NSC   128            // 16-col steps per wave
#define NBLK  1024           // R_TOT / 16

// Output layout (floats)
#define MASK_OFF 0
#define LOGP_OFF 16384
#define WORD_OFF 32768
#define CHAR_OFF 49152
#define EMB_OFF  376832          // 49152 + 16384*20
#define LOSS_OFF 2473984         // 376832 + 16384*128

// ws layout (float slots)
#define X_OFF     0              // x f32 [16384][128]
#define HDN_OFF   2097152        // hdn f32 [16384][512]
#define HDNB_OFF  10485760       // hdn bf16 ushort[16384*512]
#define WT_OFF    14680064       // wtgt f32 [2048][128]; reused as entP/cntP after k1b
#define WTT4_OFF  14942208       // wtgtT4 ushort[128][8][64][8]   (524288)
#define W2T_OFF   15204352       // W2Tf f32 [2048][512]
#define W2P_OFF   16252928       // W2p3 ushort[128][2][8][512]    (1048576)

typedef __attribute__((ext_vector_type(8))) short short8v;
typedef __attribute__((ext_vector_type(4))) float f32x4;
typedef unsigned short ushort_t;

__device__ __forceinline__ ushort_t f2bf(float f) {
    union { float f; unsigned int u; } v; v.f = f;
    unsigned int r = v.u + 0x7FFFu + ((v.u >> 16) & 1u);
    return (ushort_t)(r >> 16);
}

__device__ __forceinline__ void stage16(const ushort_t* gsrc, ushort_t* ldst) {
    __builtin_amdgcn_global_load_lds(
        (const __attribute__((address_space(1))) unsigned int*)gsrc,
        (__attribute__((address_space(3))) unsigned int*)ldst, 16, 0, 0);
}
#define VM_FENCE() asm volatile("" ::: "memory")

// ---------------- K1: gather embeddings ----------------
__global__ __launch_bounds__(256) void k1_gather(
    const int* __restrict__ inp_word, const int* __restrict__ tgt_ids,
    const float* __restrict__ W, float* __restrict__ x, float* __restrict__ wtgt)
{
    int row = blockIdx.x * 2 + (threadIdx.x >> 7);
    int d = threadIdx.x & 127;
    if (row < R_TOT) {
        int wsrc = inp_word[row];
        x[(size_t)row * DD + d] = W[(size_t)wsrc * DD + d];
    } else {
        int rr = row - R_TOT;
        if (rr < T_NT) {
            int wsrc = tgt_ids[rr];
            wtgt[(size_t)rr * DD + d] = W[(size_t)wsrc * DD + d];
        }
    }
}

// ---------------- K1b: wtgt -> wtgtT4 PV B-fragment pack ----------------
// wtgtT4[(sc*8+df)*512 + lane*8 + j] = j<4 ? bf16(wtgt[sc*16+(lane>>4)*4+j][df*16+(lane&15)]) : 0
__global__ __launch_bounds__(256) void k1b_wtgtT4(
    const float* __restrict__ wtgt, ushort_t* __restrict__ wtgtT4)
{
    const int js = blockIdx.x, t = threadIdx.x;
    #pragma unroll
    for (int i = 0; i < 4; ++i) {
        int s = i * 256 + t;
        int cs = s >> 9, rem = s & 511;
        int df = rem >> 6, lane = rem & 63;
        int lrow = lane & 15, kg = lane >> 4;
        ushort_t* dst = wtgtT4 + (size_t)(((js * 2 + cs) * 8 + df) * 512 + lane * 8);
        #pragma unroll
        for (int j = 0; j < 8; ++j) {
            dst[j] = (j < 4)
                ? f2bf(wtgt[(size_t)(js * 32 + cs * 16 + kg * 4 + j) * DD + df * 16 + lrow])
                : (ushort_t)0;
        }
    }
}

// ---------------- K0: W2 [512][2048] -> W2Tf f32 + W2p3 halved fragment pack ----------------
// W2p3[((sc)*2 + kh)*4096 + ksl*512 + (cl*4+kgrp)*8 + i] = bf16(W2[(kh*8+ksl)*32+kgrp*8+i][sc*16+cl])
__global__ __launch_bounds__(256) void k0_w2t(
    const float* __restrict__ W2, float* __restrict__ W2Tf, ushort_t* __restrict__ W2p3)
{
    __shared__ float tile[32][33];
    const int js = blockIdx.x, ks = blockIdx.y;
    const int cb = js * 32, kb = ks * 32;
    const int lx = threadIdx.x & 31, ly = threadIdx.x >> 5;
    #pragma unroll
    for (int i = 0; i < 32; i += 8)
        tile[ly + i][lx] = W2[(size_t)(kb + ly + i) * T_NT + cb + lx];
    __syncthreads();
    #pragma unroll
    for (int i = 0; i < 32; i += 8)
        W2Tf[(size_t)(cb + ly + i) * HH + kb + lx] = tile[lx][ly + i];
    if (threadIdx.x < 128) {
        int c = threadIdx.x >> 2, kgrp = threadIdx.x & 3;
        int cs = c >> 4, cl = c & 15;
        ushort_t* dst = W2p3 + (size_t)(((js * 2 + cs) * 2 + (ks >> 3)) * 4096
                                        + (ks & 7) * 512 + (cl * 4 + kgrp) * 8);
        #pragma unroll
        for (int i = 0; i < 8; ++i)
            dst[i] = f2bf(tile[kgrp * 8 + i][cb + c - cb]);   // tile[k-local][c]
    }
}

// ---------------- K2: hdn = relu(x @ W1 + b1), fp32 + bf16 outputs ----------------
__global__ __launch_bounds__(256) void k2_hdn(
    const float* __restrict__ x, const float* __restrict__ W1,
    const float* __restrict__ b1, float* __restrict__ hdn, ushort_t* __restrict__ hdnB)
{
    __shared__ float As[16][64];
    __shared__ float Bs[16][64];
    const int t = threadIdx.x;
    const int bm = blockIdx.x * 64;
    const int bn = blockIdx.y * 64;
    const int tx = t & 15, ty = t >> 4;
    float acc[4][4] = {};
    for (int k0 = 0; k0 < DD; k0 += 16) {
        {
            int m = t >> 2, kq = t & 3;
            float4 v = *(const float4*)(x + (size_t)(bm + m) * DD + k0 + kq * 4);
            As[kq * 4 + 0][m] = v.x; As[kq * 4 + 1][m] = v.y;
            As[kq * 4 + 2][m] = v.z; As[kq * 4 + 3][m] = v.w;
        }
        {
            int k = t >> 4, nq = t & 15;
            *(float4*)(&Bs[k][nq * 4]) =
                *(const float4*)(W1 + (size_t)(k0 + k) * HH + bn + nq * 4);
        }
        __syncthreads();
        #pragma unroll
        for (int k = 0; k < 16; ++k) {
            float a[4], b[4];
            #pragma unroll
            for (int i = 0; i < 4; i++) a[i] = As[k][ty * 4 + i];
            #pragma unroll
            for (int j = 0; j < 4; j++) b[j] = Bs[k][tx * 4 + j];
            #pragma unroll
            for (int i = 0; i < 4; i++)
                #pragma unroll
                for (int j = 0; j < 4; j++)
                    acc[i][j] = fmaf(a[i], b[j], acc[i][j]);
        }
        __syncthreads();
    }
    #pragma unroll
    for (int i = 0; i < 4; i++) {
        int m = bm + ty * 4 + i;
        int n = bn + tx * 4;
        float4 v;
        v.x = fmaxf(acc[i][0] + b1[n + 0], 0.f);
        v.y = fmaxf(acc[i][1] + b1[n + 1], 0.f);
        v.z = fmaxf(acc[i][2] + b1[n + 2], 0.f);
        v.w = fmaxf(acc[i][3] + b1[n + 3], 0.f);
        *(float4*)(hdn + (size_t)m * HH + n) = v;
        ushort4 hb;
        hb.x = f2bf(v.x); hb.y = f2bf(v.y); hb.z = f2bf(v.z); hb.w = f2bf(v.w);
        *(ushort4*)(hdnB + (size_t)m * HH + n) = hb;
    }
}

// ---------------- K3: 1-wave blocks, zero barriers, counted-vmcnt pipeline ----------------
// 1024 blocks x 64 threads. Each wave: 16 rows x all 2048 cols (128 steps of 16).
__global__ __launch_bounds__(64, 2) void k3_fused(
    const ushort_t* __restrict__ hdnB, const float* __restrict__ hdn,
    const ushort_t* __restrict__ W2p3, const float* __restrict__ W2Tf,
    const float* __restrict__ b2, const float* __restrict__ gumbel,
    const int* __restrict__ inp_word, const int* __restrict__ keyword_table,
    const int* __restrict__ tgt_ids, const int* __restrict__ lut,
    const float* __restrict__ x, const ushort_t* __restrict__ wtgtT4,
    float* __restrict__ out, float* __restrict__ entP, float* __restrict__ cntP)
{
    __shared__ ushort_t bS[2][4096];   // two private 8KB K-half buffers
    __shared__ float pS[16 * 20];      // P transpose tile (pad 20)

    const int lane = threadIdx.x;
    const int lrow = lane & 15, kgrp = lane >> 4;
    const int row0 = blockIdx.x * 16;

    // ---- A fragments: full K in registers ----
    short8v av[16];
    #pragma unroll
    for (int ks = 0; ks < 16; ++ks)
        av[ks] = *(const short8v*)(hdnB + (size_t)(row0 + lrow) * HH + ks * 32 + kgrp * 8);
    asm volatile("s_waitcnt vmcnt(0)" ::: "memory");   // clean vmcnt slate

    const int sc0 = blockIdx.x & 127;  // rotated start column-step

    const ushort_t* wsrc = W2p3 + lane * 8;
    ushort_t* dst0 = &bS[0][0] + lane * 8;
    ushort_t* dst1 = &bS[1][0] + lane * 8;
    const ushort_t* brd = &bS[0][0] + (lrow * 4 + kgrp) * 8;

    const float* gbase = gumbel + (size_t)(row0 + kgrp * 4) * T_NT + lrow;
    const float* b2base = b2 + lrow;
    const ushort_t* vbase = wtgtT4 + lane * 8;

    float m_[4], sE_[4], sEl_[4], s2_[4], a1_[4], a2_[4];
    int i1_[4], i2_[4];
    #pragma unroll
    for (int q = 0; q < 4; ++q) {
        m_[q] = -1e30f; sE_[q] = 0.f; sEl_[q] = 0.f; s2_[q] = 0.f;
        a1_[q] = -1e30f; a2_[q] = -1e30f; i1_[q] = 0; i2_[q] = 0;
    }
    f32x4 accpv[8];
    #pragma unroll
    for (int df = 0; df < 8; ++df) accpv[df] = (f32x4){0.f, 0.f, 0.f, 0.f};

    // ---- prologue: [stage h0(sc0): 8][gcur: 4][stage h1(sc0): 8] -> outstanding 20 ----
    {
        const ushort_t* s0 = wsrc + (size_t)sc0 * 8192;
        #pragma unroll
        for (int i = 0; i < 8; ++i) stage16(s0 + i * 512, dst0 + i * 512);
    }
    VM_FENCE();
    float g0 = gbase[(size_t)0 * T_NT + sc0 * 16];
    float g1 = gbase[(size_t)1 * T_NT + sc0 * 16];
    float g2 = gbase[(size_t)2 * T_NT + sc0 * 16];
    float g3 = gbase[(size_t)3 * T_NT + sc0 * 16];
    VM_FENCE();
    {
        const ushort_t* s1 = wsrc + (size_t)sc0 * 8192 + 4096;
        #pragma unroll
        for (int i = 0; i < 8; ++i) stage16(s1 + i * 512, dst1 + i * 512);
    }
    VM_FENCE();

    for (int s = 0; s < NSC; ++s) {
        const int sc = (sc0 + s) & 127;
        const int scn = (sc0 + s + 1) & 127;
        const int colv = sc * 16 + lrow;

        // top loads: bvf[8] + b2 (9 VMEM)
        short8v bvf[8];
        const ushort_t* vp = vbase + (size_t)sc * 4096;
        #pragma unroll
        for (int df = 0; df < 8; ++df) bvf[df] = *(const short8v*)(vp + df * 512);
        float b2v = b2base[sc * 16];

        asm volatile("s_waitcnt vmcnt(21)" ::: "memory");   // h0(sc) landed

        // S part 1: K 0..255 from buf0
        f32x4 ac0 = (f32x4){0.f,0.f,0.f,0.f}, ac1 = ac0, ac2 = ac0, ac3 = ac0;
        #pragma unroll
        for (int ks = 0; ks < 8; ks += 4) {
            ac0 = __builtin_amdgcn_mfma_f32_16x16x32_bf16(av[ks+0], *(const short8v*)(brd + (ks+0)*512), ac0, 0, 0, 0);
            ac1 = __builtin_amdgcn_mfma_f32_16x16x32_bf16(av[ks+1], *(const short8v*)(brd + (ks+1)*512), ac1, 0, 0, 0);
            ac2 = __builtin_amdgcn_mfma_f32_16x16x32_bf16(av[ks+2], *(const short8v*)(brd + (ks+2)*512), ac2, 0, 0, 0);
            ac3 = __builtin_amdgcn_mfma_f32_16x16x32_bf16(av[ks+3], *(const short8v*)(brd + (ks+3)*512), ac3, 0, 0, 0);
        }
        asm volatile("s_waitcnt lgkmcnt(0)" ::: "memory");  // buf0 reads retired

        // stage h0(next) into buf0 (8)
        {
            const ushort_t* sn0 = wsrc + (size_t)scn * 8192;
            #pragma unroll
            for (int i = 0; i < 8; ++i) stage16(sn0 + i * 512, dst0 + i * 512);
        }
        VM_FENCE();
        // gnext (4)
        float gn0 = gbase[(size_t)0 * T_NT + scn * 16];
        float gn1 = gbase[(size_t)1 * T_NT + scn * 16];
        float gn2 = gbase[(size_t)2 * T_NT + scn * 16];
        float gn3 = gbase[(size_t)3 * T_NT + scn * 16];

        asm volatile("s_waitcnt vmcnt(12)" ::: "memory");   // h1(sc), gcur, bvf, b2 ready

        // S part 2: K 256..511 from buf1
        #pragma unroll
        for (int ks = 8; ks < 16; ks += 4) {
            ac0 = __builtin_amdgcn_mfma_f32_16x16x32_bf16(av[ks+0], *(const short8v*)(brd + 4096 + (ks-8+0)*512), ac0, 0, 0, 0);
            ac1 = __builtin_amdgcn_mfma_f32_16x16x32_bf16(av[ks+1], *(const short8v*)(brd + 4096 + (ks-8+1)*512), ac1, 0, 0, 0);
            ac2 = __builtin_amdgcn_mfma_f32_16x16x32_bf16(av[ks+2], *(const short8v*)(brd + 4096 + (ks-8+2)*512), ac2, 0, 0, 0);
            ac3 = __builtin_amdgcn_mfma_f32_16x16x32_bf16(av[ks+3], *(const short8v*)(brd + 4096 + (ks-8+3)*512), ac3, 0, 0, 0);
        }
        f32x4 acc = (ac0 + ac1) + (ac2 + ac3);

        // stats + top2 + P write
        float g4[4] = {g0, g1, g2, g3};
        #pragma unroll
        for (int q = 0; q < 4; ++q) {
            float l = acc[q] + b2v;
            m_[q] = fmaxf(m_[q], l);
            float e1 = __expf(l);
            sE_[q] += e1; sEl_[q] = fmaf(e1, l, sEl_[q]);
            float a = l + g4[q];
            float p = __expf(2.0f * a);
            s2_[q] += p;
            if (a > a1_[q]) { a2_[q] = a1_[q]; i2_[q] = i1_[q]; a1_[q] = a; i1_[q] = colv; }
            else if (a > a2_[q]) { a2_[q] = a; i2_[q] = colv; }
            pS[(kgrp * 4 + q) * 20 + lrow] = p;
        }

        // PV: transpose-read own P, K=16 zero-padded MFMA
        {
            float4 p4 = *(const float4*)(&pS[lrow * 20 + kgrp * 4]);
            short8v pav;
            pav[0] = (short)f2bf(p4.x); pav[1] = (short)f2bf(p4.y);
            pav[2] = (short)f2bf(p4.z); pav[3] = (short)f2bf(p4.w);
            pav[4] = 0; pav[5] = 0; pav[6] = 0; pav[7] = 0;
            #pragma unroll
            for (int df = 0; df < 8; ++df)
                accpv[df] = __builtin_amdgcn_mfma_f32_16x16x32_bf16(pav, bvf[df], accpv[df], 0, 0, 0);
        }

        asm volatile("s_waitcnt lgkmcnt(0)" ::: "memory");  // buf1 reads + P ops retired
        // stage h1(next) into buf1 (8)
        {
            const ushort_t* sn1 = wsrc + (size_t)scn * 8192 + 4096;
            #pragma unroll
            for (int i = 0; i < 8; ++i) stage16(sn1 + i * 512, dst1 + i * 512);
        }
        VM_FENCE();

        g0 = gn0; g1 = gn1; g2 = gn2; g3 = gn3;
    }

    // ---- epilogue (single wave; no barriers) ----
    #pragma unroll
    for (int q = 0; q < 4; ++q) {
        #pragma unroll
        for (int mk = 1; mk < 16; mk <<= 1) {
            m_[q] = fmaxf(m_[q], __shfl_xor(m_[q], mk));
            sE_[q] += __shfl_xor(sE_[q], mk);
            sEl_[q] += __shfl_xor(sEl_[q], mk);
            s2_[q] += __shfl_xor(s2_[q], mk);
            float ob1 = __shfl_xor(a1_[q], mk); int oj1 = __shfl_xor(i1_[q], mk);
            float ob2 = __shfl_xor(a2_[q], mk); int oj2 = __shfl_xor(i2_[q], mk);
            if (ob1 > a1_[q] || (ob1 == a1_[q] && oj1 < i1_[q])) {
                if (a1_[q] > ob2 || (a1_[q] == ob2 && i1_[q] < oj2)) { a2_[q] = a1_[q]; i2_[q] = i1_[q]; }
                else { a2_[q] = ob2; i2_[q] = oj2; }
                a1_[q] = ob1; i1_[q] = oj1;
            } else {
                if (ob1 > a2_[q]) { a2_[q] = ob1; i2_[q] = oj1; }
            }
        }
    }

    float invs2_[4]; int msk_[4];
    #pragma unroll
    for (int q = 0; q < 4; ++q) {
        invs2_[q] = 1.0f / s2_[q];
        int w_in = inp_word[row0 + kgrp * 4 + q];
        msk_[q] = keyword_table[w_in] != 0;
    }

    // x_emb store
    #pragma unroll
    for (int df = 0; df < 8; ++df) {
        #pragma unroll
        for (int q = 0; q < 4; ++q) {
            int grow = row0 + kgrp * 4 + q;
            int d = df * 16 + lrow;
            float val = accpv[df][q] * invs2_[q];
            if (!msk_[q]) val = x[(size_t)grow * DD + d];
            out[EMB_OFF + (size_t)grow * DD + d] = val;
        }
    }

    // scalar outputs + loss partials
    float es = 0.f; int cs = 0;
    #pragma unroll
    for (int q = 0; q < 4; ++q) {
        float entq = msk_[q] ? (__logf(sE_[q]) - sEl_[q] / sE_[q]) : 0.0f;
        es += entq; cs += msk_[q];
        if (lrow == 0) {
            int grow = row0 + kgrp * 4 + q;
            out[MASK_OFF + grow] = msk_[q] ? 1.0f : 0.0f;
            out[LOGP_OFF + grow] = msk_[q] ? m_[q] : 0.0f;
        }
    }
    {
        float e0 = __shfl(es, 0), e16 = __shfl(es, 16), e32 = __shfl(es, 32), e48 = __shfl(es, 48);
        int c0 = __shfl(cs, 0), c16 = __shfl(cs, 16), c32 = __shfl(cs, 32), c48 = __shfl(cs, 48);
        if (lane == 0) {
            entP[blockIdx.x] = e0 + e16 + e32 + e48;
            cntP[blockIdx.x] = (float)(c0 + c16 + c32 + c48);
        }
    }

    // repair + word/char outputs
    #pragma unroll
    for (int rr = 0; rr < 16; ++rr) {
        const int q = rr & 3, sl = (rr >> 2) << 4;
        int i1 = __shfl(i1_[q], sl);
        int i2 = __shfl(i2_[q], sl);
        int mskr = __shfl(msk_[q], sl);
        int grow = row0 + rr;
        const float* hrow = hdn + (size_t)grow * HH;
        float4 h0 = *(const float4*)(hrow + lane * 8);
        float4 h1 = *(const float4*)(hrow + lane * 8 + 4);
        float v1, v2;
        {
            const float* wrow = W2Tf + (size_t)i1 * HH;
            float4 w0 = *(const float4*)(wrow + lane * 8);
            float4 w1 = *(const float4*)(wrow + lane * 8 + 4);
            float sdot = h0.x*w0.x + h0.y*w0.y + h0.z*w0.z + h0.w*w0.w
                       + h1.x*w1.x + h1.y*w1.y + h1.z*w1.z + h1.w*w1.w;
            #pragma unroll
            for (int mk = 1; mk < 64; mk <<= 1) sdot += __shfl_xor(sdot, mk);
            v1 = sdot + b2[i1] + gumbel[(size_t)grow * T_NT + i1];
        }
        {
            const float* wrow = W2Tf + (size_t)i2 * HH;
            float4 w0 = *(const float4*)(wrow + lane * 8);
            float4 w1 = *(const float4*)(wrow + lane * 8 + 4);
            float sdot = h0.x*w0.x + h0.y*w0.y + h0.z*w0.z + h0.w*w0.w
                       + h1.x*w1.x + h1.y*w1.y + h1.z*w1.z + h1.w*w1.w;
            #pragma unroll
            for (int mk = 1; mk < 64; mk <<= 1) sdot += __shfl_xor(sdot, mk);
            v2 = sdot + b2[i2] + gumbel[(size_t)grow * T_NT + i2];
        }
        int ibest = (v2 > v1 || (v2 == v1 && i2 < i1)) ? i2 : i1;
        int word = mskr ? tgt_ids[ibest] : inp_word[grow];
        if (lane == 0) out[WORD_OFF + grow] = (float)word;
        if (lane < MC_)
            out[CHAR_OFF + (size_t)grow * MC_ + lane] = (float)lut[(size_t)word * MC_ + lane];
    }
}

// ---------------- K4: final loss reduction ----------------
__global__ __launch_bounds__(256) void k4_loss(
    const float* __restrict__ entP, const float* __restrict__ cntP, float* __restrict__ out)
{
    __shared__ float sE[256], sC[256];
    int t = threadIdx.x;
    float e = 0.f, c = 0.f;
    for (int i = t; i < NBLK; i += 256) { e += entP[i]; c += cntP[i]; }
    sE[t] = e; sC[t] = c;
    __syncthreads();
    for (int s = 128; s > 0; s >>= 1) {
        if (t < s) { sE[t] += sE[t + s]; sC[t] += sC[t + s]; }
        __syncthreads();
    }
    if (t == 0) {
        float ns = fmaxf(sC[0], 1.0f);
        out[LOSS_OFF] = 0.03f * sE[0] / ns;
    }
}

// ---------------- launch ----------------
extern "C" void kernel_launch(void* const* d_in, const int* in_sizes, int n_in,
                              void* d_out, int out_size, void* d_ws, size_t ws_size,
                              hipStream_t stream) {
    const int* inp_word = (const int*)d_in[0];
    const int* keyword_table = (const int*)d_in[3];
    const int* tgt_ids = (const int*)d_in[4];
    const int* lut = (const int*)d_in[5];
    const float* gumbel = (const float*)d_in[6];
    const float* W = (const float*)d_in[7];
    const float* W1 = (const float*)d_in[8];
    const float* b1 = (const float*)d_in[9];
    const float* W2 = (const float*)d_in[10];
    const float* b2 = (const float*)d_in[11];
    float* out = (float*)d_out;

    float* wsf = (float*)d_ws;
    float* x = wsf + X_OFF;
    float* hdn = wsf + HDN_OFF;
    ushort_t* hdnB = (ushort_t*)(wsf + HDNB_OFF);
    float* wtgt = wsf + WT_OFF;
    ushort_t* wtgtT4 = (ushort_t*)(wsf + WTT4_OFF);
    float* W2Tf = wsf + W2T_OFF;
    ushort_t* W2p3 = (ushort_t*)(wsf + W2P_OFF);
    float* entP = wsf + WT_OFF;          // wtgt region is dead after k1b
    float* cntP = wsf + WT_OFF + 1024;

    k1_gather<<<(R_TOT + T_NT) / 2, 256, 0, stream>>>(inp_word, tgt_ids, W, x, wtgt);
    k1b_wtgtT4<<<64, 256, 0, stream>>>(wtgt, wtgtT4);
    k0_w2t<<<dim3(T_NT / 32, HH / 32), 256, 0, stream>>>(W2, W2Tf, W2p3);
    k2_hdn<<<dim3(R_TOT / 64, HH / 64), 256, 0, stream>>>(x, W1, b1, hdn, hdnB);
    k3_fused<<<NBLK, 64, 0, stream>>>(hdnB, hdn, W2p3, W2Tf, b2, gumbel,
                                      inp_word, keyword_table, tgt_ids, lut,
                                      x, wtgtT4, out, entP, cntP);
    k4_loss<<<1, 256, 0, stream>>>(entP, cntP, out);
}